// Round 2
// baseline (17055.586 us; speedup 1.0000x reference)
//
#include <hip/hip_runtime.h>
#include <math.h>

// S3Tokenizer (Whisper-style encoder + VQ argmax) on MI355X.
// Strategy: all matmuls via one split-bf16 3-MFMA GEMM (fp32-accurate to ~2^-16),
// fp32 activations everywhere, fused epilogues, in-place softmax.
// Output dtype is INT32 (code, code_len) — harness reads d_out as int32.

#define DEVI __device__ __forceinline__

typedef __attribute__((ext_vector_type(8))) __bf16 bf16x8;
typedef __attribute__((ext_vector_type(4))) float f32x4;

DEVI float bitf(unsigned u){ return __builtin_bit_cast(float, u); }
DEVI unsigned fbit(float f){ return __builtin_bit_cast(unsigned, f); }
DEVI float gelu_f(float x){ return 0.5f*x*(1.0f + erff(x*0.7071067811865475f)); }

// ---------------- GEMM: C[M,N] = epi(A[M,K] @ B[N,K]^T) ----------------
// fp32 in/out; internally split each operand to (hi,lo) bf16 during LDS staging,
// 3 MFMAs per fragment pair (hi*hi + hi*lo + lo*hi), fp32 accum.
// LDS XOR-swizzle: addr = (r*64 + cbyte) ^ ((r&7)<<4)  (bijective; spreads the
// stride-64B rows over 8 distinct 16B slots -> 2-way (free) ds_read_b128).
// EPI: 0: (acc+bias)*scale   1: gelu(acc+bias)   2: C += acc+bias (residual)
//      3: gelu(acc+bias) + aux[(row%750)*1280+col]   (conv2 + pos_emb)

DEVI void stage_tile(const float* __restrict__ src, int ld, int nrows, int rowBase,
                     int kBase, int K, int tid, char* dh, char* dl)
{
    #pragma unroll
    for (int i = 0; i < 4; ++i){
        int f  = tid + (i << 8);      // 0..1023 float4s
        int r  = f >> 3;              // tile row 0..127
        int c4 = (f & 7) << 2;        // k within tile: 0,4,..,28
        int grow = rowBase + r;
        int gk   = kBase + c4;
        f32x4 v = {0.f, 0.f, 0.f, 0.f};
        if (grow < nrows){
            const float* p = src + (long)grow * ld + gk;
            if (gk + 3 < K){
                v = *(const f32x4*)p;
            } else {
                if (gk     < K) v.x = p[0];
                if (gk + 1 < K) v.y = p[1];
                if (gk + 2 < K) v.z = p[2];
            }
        }
        unsigned u0=fbit(v.x), u1=fbit(v.y), u2=fbit(v.z), u3=fbit(v.w);
        unsigned h01 = (u0 >> 16) | (u1 & 0xFFFF0000u);
        unsigned h23 = (u2 >> 16) | (u3 & 0xFFFF0000u);
        float r0 = v.x - bitf(u0 & 0xFFFF0000u);
        float r1 = v.y - bitf(u1 & 0xFFFF0000u);
        float r2 = v.z - bitf(u2 & 0xFFFF0000u);
        float r3 = v.w - bitf(u3 & 0xFFFF0000u);
        unsigned l01 = (fbit(r0) >> 16) | (fbit(r1) & 0xFFFF0000u);
        unsigned l23 = (fbit(r2) >> 16) | (fbit(r3) & 0xFFFF0000u);
        int ad = ((r << 6) + (c4 << 1)) ^ ((r & 7) << 4);
        uint2 uh; uh.x = h01; uh.y = h23;
        uint2 ul; ul.x = l01; ul.y = l23;
        *(uint2*)(dh + ad) = uh;
        *(uint2*)(dl + ad) = ul;
    }
}

template<int EPI>
__global__ __launch_bounds__(256, 2) void gemm_k(
    const float* __restrict__ A, const float* __restrict__ B, float* __restrict__ C,
    int M, int N, int K, int lda, int ldb, int ldc,
    long sAo, long sAi, int dA,
    long sBo, long sBi, int dB,
    long sCo, long sCi, int dC,
    const float* __restrict__ bias, const float* __restrict__ aux, float scale)
{
    __shared__ short AhS[4096], AlS[4096], BhS[4096], BlS[4096];
    char* pAh = (char*)AhS; char* pAl = (char*)AlS;
    char* pBh = (char*)BhS; char* pBl = (char*)BlS;

    const int tid = threadIdx.x;
    const int z = blockIdx.z;
    const float* Ab = A + (long)(z / dA) * sAo + (long)(z % dA) * sAi;
    const float* Bb = B + (long)(z / dB) * sBo + (long)(z % dB) * sBi;
    float* Cb       = C + (long)(z / dC) * sCo + (long)(z % dC) * sCi;

    const int rowBase = blockIdx.y << 7;
    const int colBase = blockIdx.x << 7;
    const int lane = tid & 63;
    const int w    = tid >> 6;
    const int wr   = (w >> 1) << 6;    // 0 / 64
    const int wc   = (w & 1) << 6;     // 0 / 64
    const int fr   = lane & 15;        // A-row / B-col within fragment
    const int kg   = lane >> 4;        // k-group (x8 elems = 16 bytes)

    f32x4 acc[4][4];
    #pragma unroll
    for (int m=0;m<4;m++)
        #pragma unroll
        for (int n=0;n<4;n++) acc[m][n] = (f32x4){0.f,0.f,0.f,0.f};

    const int KT = (K + 31) >> 5;
    for (int kt = 0; kt < KT; ++kt){
        const int kBase = kt << 5;
        __syncthreads();
        stage_tile(Ab, lda, M, rowBase, kBase, K, tid, pAh, pAl);
        stage_tile(Bb, ldb, N, colBase, kBase, K, tid, pBh, pBl);
        __syncthreads();

        bf16x8 ah[4], al[4], bh[4], bl[4];
        #pragma unroll
        for (int m=0;m<4;m++){
            int rr = wr + (m<<4) + fr;
            int ad = ((rr<<6) + (kg<<4)) ^ ((rr&7)<<4);
            ah[m] = *(const bf16x8*)(pAh + ad);
            al[m] = *(const bf16x8*)(pAl + ad);
        }
        #pragma unroll
        for (int n=0;n<4;n++){
            int rr = wc + (n<<4) + fr;
            int ad = ((rr<<6) + (kg<<4)) ^ ((rr&7)<<4);
            bh[n] = *(const bf16x8*)(pBh + ad);
            bl[n] = *(const bf16x8*)(pBl + ad);
        }
        #pragma unroll
        for (int m=0;m<4;m++){
            #pragma unroll
            for (int n=0;n<4;n++){
                acc[m][n] = __builtin_amdgcn_mfma_f32_16x16x32_bf16(ah[m], bh[n], acc[m][n], 0,0,0);
                acc[m][n] = __builtin_amdgcn_mfma_f32_16x16x32_bf16(ah[m], bl[n], acc[m][n], 0,0,0);
                acc[m][n] = __builtin_amdgcn_mfma_f32_16x16x32_bf16(al[m], bh[n], acc[m][n], 0,0,0);
            }
        }
    }

    // epilogue: C/D layout col = lane&15, row = (lane>>4)*4 + j  (m89-verified)
    #pragma unroll
    for (int n=0;n<4;n++){
        int col = colBase + wc + (n<<4) + fr;
        if (col >= N) continue;
        float bv = bias ? bias[col] : 0.f;
        #pragma unroll
        for (int m=0;m<4;m++){
            int rbase = rowBase + wr + (m<<4) + (kg<<2);
            #pragma unroll
            for (int j=0;j<4;j++){
                int row = rbase + j;
                if (row >= M) continue;
                float v = acc[m][n][j];
                float* cp = Cb + (long)row*ldc + col;
                if (EPI == 0)      *cp = (v + bv) * scale;
                else if (EPI == 1) *cp = gelu_f(v + bv);
                else if (EPI == 2) *cp = *cp + v + bv;
                else               *cp = gelu_f(v + bv) + aux[(long)(row % 750)*1280 + col];
            }
        }
    }
}

// ---------------- small kernels ----------------

__global__ __launch_bounds__(256) void ln_k(const float* __restrict__ x, float* __restrict__ h,
                                            const float* __restrict__ g, const float* __restrict__ bb)
{
    __shared__ float red[8];
    int row = blockIdx.x, tid = threadIdx.x;
    const float* xr = x + (long)row * 1280;
    float v[5]; float s = 0.f;
    #pragma unroll
    for (int i=0;i<5;i++){ v[i] = xr[tid + (i<<8)]; s += v[i]; }
    #pragma unroll
    for (int m=32;m>=1;m>>=1) s += __shfl_xor(s, m, 64);
    if ((tid & 63) == 0) red[tid>>6] = s;
    __syncthreads();
    float mean = (red[0]+red[1]+red[2]+red[3]) * (1.f/1280.f);
    float q = 0.f;
    #pragma unroll
    for (int i=0;i<5;i++){ float d = v[i]-mean; q += d*d; }
    #pragma unroll
    for (int m=32;m>=1;m>>=1) q += __shfl_xor(q, m, 64);
    __syncthreads();
    if ((tid & 63) == 0) red[tid>>6] = q;
    __syncthreads();
    float inv = 1.0f / sqrtf((red[0]+red[1]+red[2]+red[3]) * (1.f/1280.f) + 1e-5f);
    float* hr = h + (long)row * 1280;
    #pragma unroll
    for (int i=0;i<5;i++){ int c = tid + (i<<8); hr[c] = (v[i]-mean)*inv*g[c] + bb[c]; }
}

__global__ __launch_bounds__(256) void norm_k(const float* __restrict__ x, float* __restrict__ xn)
{
    __shared__ float red[8];
    int row = blockIdx.x, tid = threadIdx.x;
    const float* xr = x + (long)row * 1280;
    float v[5]; float s = 0.f;
    #pragma unroll
    for (int i=0;i<5;i++){ v[i] = xr[tid + (i<<8)]; s += v[i]*v[i]; }
    #pragma unroll
    for (int m=32;m>=1;m>>=1) s += __shfl_xor(s, m, 64);
    if ((tid & 63) == 0) red[tid>>6] = s;
    __syncthreads();
    float nrm = sqrtf(red[0]+red[1]+red[2]+red[3]);
    float sc = 1.0f / fmaxf(nrm, 1e-12f);
    float* hr = xn + (long)row * 1280;
    #pragma unroll
    for (int i=0;i<5;i++){ int c = tid + (i<<8); hr[c] = v[i]*sc; }
}

__global__ __launch_bounds__(256) void cbn2_k(const float* __restrict__ cb, float* __restrict__ cbn2)
{
    __shared__ float red[8];
    int row = blockIdx.x, tid = threadIdx.x;
    const float* cr = cb + (long)row * 1280;
    float s = 0.f;
    #pragma unroll
    for (int i=0;i<5;i++){ float t = cr[tid + (i<<8)]; s += t*t; }
    #pragma unroll
    for (int m=32;m>=1;m>>=1) s += __shfl_xor(s, m, 64);
    if ((tid & 63) == 0) red[tid>>6] = s;
    __syncthreads();
    if (tid == 0) cbn2[row] = red[0]+red[1]+red[2]+red[3];
}

// masked softmax over rows of S, in-place. S layout: [z][750][768], blockIdx.x = z*750 + r
__global__ __launch_bounds__(256) void softmax_k(float* __restrict__ S, const float* __restrict__ bv, int b0)
{
    __shared__ float red[8];
    int z = blockIdx.x / 750;
    int bg = b0 + z / 20;
    const float* bias = bv + bg * 750;
    float* Sr = S + (long)blockIdx.x * 768;
    int tid = threadIdx.x;
    float vals[3]; float mx = -3.0e38f;
    #pragma unroll
    for (int i=0;i<3;i++){
        int c = tid + (i<<8);
        if (c < 750){ vals[i] = Sr[c] + bias[c]; mx = fmaxf(mx, vals[i]); }
        else vals[i] = -3.0e38f;
    }
    #pragma unroll
    for (int m=32;m>=1;m>>=1) mx = fmaxf(mx, __shfl_xor(mx, m, 64));
    if ((tid & 63) == 0) red[tid>>6] = mx;
    __syncthreads();
    mx = fmaxf(fmaxf(red[0],red[1]), fmaxf(red[2],red[3]));
    float s = 0.f;
    #pragma unroll
    for (int i=0;i<3;i++){
        int c = tid + (i<<8);
        if (c < 750){ vals[i] = expf(vals[i] - mx); s += vals[i]; }
    }
    #pragma unroll
    for (int m=32;m>=1;m>>=1) s += __shfl_xor(s, m, 64);
    __syncthreads();
    if ((tid & 63) == 0) red[tid>>6] = s;
    __syncthreads();
    s = red[0]+red[1]+red[2]+red[3];
    float inv = 1.0f / s;
    #pragma unroll
    for (int i=0;i<3;i++){ int c = tid + (i<<8); if (c < 750) Sr[c] = vals[i]*inv; }
}

// V^T per (b,head): vT[bh][d][t], ld 752 (pad), from QKV cols [2560 + h*64 ..)
__global__ __launch_bounds__(256) void vtrans_k(const float* __restrict__ QKV, float* __restrict__ vT)
{
    __shared__ float tile[64][65];
    int bh = blockIdx.y; int b = bh / 20, hh = bh % 20;
    int t0 = blockIdx.x * 64;
    int tid = threadIdx.x;
    int tj = tid & 63;       // inner (d for load / t for store)
    int ti4 = tid >> 6;      // 0..3
    #pragma unroll
    for (int i=0;i<16;i++){
        int tt = ti4 + i*4;
        int t = t0 + tt;
        float val = 0.f;
        if (t < 750) val = QKV[((long)(b*750 + t))*3840 + 2560 + hh*64 + tj];
        tile[tt][tj] = val;
    }
    __syncthreads();
    #pragma unroll
    for (int i=0;i<16;i++){
        int d = ti4 + i*4;
        int t = t0 + tj;
        if (t < 750) vT[((long)(bh*64 + d))*752 + t] = tile[tj][d];
    }
}

// im2col for conv1: A1[(b*1500+t)][i*3+k] = mel[b][i][2t-1+k]
__global__ __launch_bounds__(128) void im2col1_k(const float* __restrict__ mel, float* __restrict__ A1)
{
    int row = blockIdx.x;            // b*1500 + t
    int b = row / 1500, t = row % 1500;
    int i = threadIdx.x;             // 0..127
    float* outp = A1 + (long)row*384 + i*3;
    const float* mp = mel + ((long)(b*128 + i))*3000;
    #pragma unroll
    for (int k=0;k<3;k++){
        int u = 2*t - 1 + k;
        outp[k] = (u >= 0 && u < 3000) ? mp[u] : 0.f;
    }
}

// im2col for conv2: A2[(b*750+t)][i*3+k] = y1[(b*1500 + 2t-1+k)][i]
__global__ __launch_bounds__(256) void im2col2_k(const float* __restrict__ y1, float* __restrict__ A2)
{
    int row = blockIdx.x;            // b*750 + t
    int b = row / 750, t = row % 750;
    int tid = threadIdx.x;
    for (int s=0;s<5;s++){
        int i = tid + (s<<8);        // 0..1279
        float* outp = A2 + (long)row*3840 + i*3;
        #pragma unroll
        for (int k=0;k<3;k++){
            int u = 2*t - 1 + k;
            outp[k] = (u >= 0 && u < 1500) ? y1[((long)(b*1500 + u))*1280 + i] : 0.f;
        }
    }
}

__global__ void biasv_k(const int* __restrict__ mel_len, float* __restrict__ bv)
{
    int idx = blockIdx.x*256 + threadIdx.x;
    if (idx < 6000){
        int b = idx / 750, t = idx % 750;
        bv[idx] = (4*t + 3 < mel_len[b]) ? 0.f : -1e10f;
    }
}

__global__ __launch_bounds__(256) void argmax_k(const float* __restrict__ dist, const float* __restrict__ cbn2,
                                                int* __restrict__ outp)
{
    __shared__ float bvs[256];
    __shared__ int   bis[256];
    int row = blockIdx.x, tid = threadIdx.x;
    const float* dr = dist + (long)row * 4096;
    float best = -3.0e38f; int bidx = 0x7fffffff;
    for (int i=0;i<16;i++){
        int n = tid + (i<<8);
        float v = 2.f*dr[n] - cbn2[n];
        if (v > best || (v == best && n < bidx)){ best = v; bidx = n; }
    }
    bvs[tid] = best; bis[tid] = bidx;
    __syncthreads();
    for (int s=128;s>0;s>>=1){
        if (tid < s){
            if (bvs[tid+s] > bvs[tid] || (bvs[tid+s] == bvs[tid] && bis[tid+s] < bis[tid])){
                bvs[tid] = bvs[tid+s]; bis[tid] = bis[tid+s];
            }
        }
        __syncthreads();
    }
    if (tid == 0) outp[row] = bis[0];   // INT32 output
}

__global__ void clen_k(const int* __restrict__ mel_len, int* __restrict__ outp)
{
    int b = threadIdx.x;
    if (b < 8){
        int l1 = (mel_len[b] + 1) >> 1;
        int l2 = (l1 + 1) >> 1;
        outp[6000 + b] = l2;            // INT32 output
    }
}

// ---------------- host ----------------

extern "C" void kernel_launch(void* const* d_in, const int* in_sizes, int n_in,
                              void* d_out, int out_size, void* d_ws, size_t ws_size,
                              hipStream_t stream)
{
    const float* mel      = (const float*)d_in[0];
    const int*   mel_len  = (const int*)  d_in[1];
    const float* conv1_w  = (const float*)d_in[2];
    const float* conv1_b  = (const float*)d_in[3];
    const float* conv2_w  = (const float*)d_in[4];
    const float* conv2_b  = (const float*)d_in[5];
    const float* pos_emb  = (const float*)d_in[6];
    const float* ln1_g    = (const float*)d_in[7];
    const float* ln1_b    = (const float*)d_in[8];
    const float* q_w      = (const float*)d_in[9];
    const float* q_b      = (const float*)d_in[10];
    const float* k_w      = (const float*)d_in[11];
    const float* v_w      = (const float*)d_in[12];
    const float* v_b      = (const float*)d_in[13];
    const float* o_w      = (const float*)d_in[14];
    const float* o_b      = (const float*)d_in[15];
    const float* ln2_g    = (const float*)d_in[16];
    const float* ln2_b    = (const float*)d_in[17];
    const float* fc1_w    = (const float*)d_in[18];
    const float* fc1_b    = (const float*)d_in[19];
    const float* fc2_w    = (const float*)d_in[20];
    const float* fc2_b    = (const float*)d_in[21];
    const float* codebook = (const float*)d_in[22];
    int* outp = (int*)d_out;
    float* ws = (float*)d_ws;

    // workspace layout (floats)
    const size_t o_x   = 0;                       // 6000x1280
    const size_t o_h   = o_x   + 7680000;         // 6000x1280
    const size_t o_qkv = o_h   + 7680000;         // 6000x3840
    const size_t o_vt  = o_qkv + 23040000;        // 160x64x752
    const size_t o_a   = o_vt  + 7700480;         // 6000x1280
    const size_t o_g   = o_a   + 7680000;         // 6000x5120 (also A1+y1 in conv phase, dist at end)
    const size_t o_cb  = o_g   + 30720000;        // 4096
    const size_t o_bv  = o_cb  + 4096;            // 6000 (pad 8192)
    const size_t o_S   = o_bv  + 8192;            // attention scores/probs (chunked), also A2 in conv phase

    float* x    = ws + o_x;
    float* h    = ws + o_h;
    float* qkv  = ws + o_qkv;
    float* vt   = ws + o_vt;
    float* ab   = ws + o_a;
    float* g    = ws + o_g;
    float* cbn2 = ws + o_cb;
    float* bv   = ws + o_bv;
    float* Sb   = ws + o_S;
    float* A1   = g;
    float* y1   = g + 4608000;   // 12000x1280 after A1 (12000x384)
    float* A2   = Sb;            // 6000x3840 == 23.04M floats (needs nb>=2 S region)
    float* dist = g;             // 6000x4096

    // choose attention batch-chunk size by available workspace
    int nb = 2;
    if      (ws_size >= (o_S + (size_t)8*20*750*768)*4 + 1024) nb = 8;
    else if (ws_size >= (o_S + (size_t)4*20*750*768)*4 + 1024) nb = 4;
    int nch = 8 / nb;

    biasv_k<<<24, 256, 0, stream>>>(mel_len, bv);
    cbn2_k<<<4096, 256, 0, stream>>>(codebook, cbn2);

    // conv1: y1[12000x1280] = gelu(A1 @ W1^T + b1)
    im2col1_k<<<12000, 128, 0, stream>>>(mel, A1);
    {
        dim3 grid(10, 94, 1);
        gemm_k<1><<<grid, 256, 0, stream>>>(A1, conv1_w, y1, 12000,1280,384, 384,384,1280,
            0,0,1, 0,0,1, 0,0,1, conv1_b, nullptr, 1.f);
    }
    // conv2 + transpose + pos_emb: x[6000x1280]
    im2col2_k<<<6000, 256, 0, stream>>>(y1, A2);
    {
        dim3 grid(10, 47, 1);
        gemm_k<3><<<grid, 256, 0, stream>>>(A2, conv2_w, x, 6000,1280,3840, 3840,3840,1280,
            0,0,1, 0,0,1, 0,0,1, conv2_b, pos_emb, 1.f);
    }

    const float qsc = 0.35355339059327373f; // 64^-0.25
    dim3 gq(10, 47, 1);
    for (int l = 0; l < 6; ++l){
        ln_k<<<6000, 256, 0, stream>>>(x, h, ln1_g + l*1280, ln1_b + l*1280);
        gemm_k<0><<<gq,256,0,stream>>>(h, q_w + (size_t)l*1638400, qkv,      6000,1280,1280, 1280,1280,3840,
            0,0,1, 0,0,1, 0,0,1, q_b + l*1280, nullptr, qsc);
        gemm_k<0><<<gq,256,0,stream>>>(h, k_w + (size_t)l*1638400, qkv+1280, 6000,1280,1280, 1280,1280,3840,
            0,0,1, 0,0,1, 0,0,1, nullptr, nullptr, qsc);
        gemm_k<0><<<gq,256,0,stream>>>(h, v_w + (size_t)l*1638400, qkv+2560, 6000,1280,1280, 1280,1280,3840,
            0,0,1, 0,0,1, 0,0,1, v_b + l*1280, nullptr, 1.f);
        vtrans_k<<<dim3(12,160), 256, 0, stream>>>(qkv, vt);

        for (int c = 0; c < nch; ++c){
            int b0 = c * nb;
            const float* qA = qkv + (size_t)b0*2880000;       // 750*3840 per b
            const float* kB = qA + 1280;
            dim3 gs(6, 6, nb*20);
            // S[z][750<=768] = q k^T  (q,k already scaled)
            gemm_k<0><<<gs,256,0,stream>>>(qA, kB, Sb, 750,750,64, 3840,3840,768,
                2880000,64,20, 2880000,64,20, 576000,0,1, nullptr, nullptr, 1.f);
            softmax_k<<<nb*20*750, 256, 0, stream>>>(Sb, bv, b0);
            dim3 gp(1, 6, nb*20);
            // a[b, t, h*64+d] = P @ V
            gemm_k<0><<<gp,256,0,stream>>>(Sb, vt + (size_t)b0*20*48128, ab + (size_t)b0*960000,
                750,64,750, 768,752,1280,
                576000,0,1, 48128,0,1, 960000,64,20, nullptr, nullptr, 1.f);
        }

        gemm_k<2><<<gq,256,0,stream>>>(ab, o_w + (size_t)l*1638400, x, 6000,1280,1280, 1280,1280,1280,
            0,0,1, 0,0,1, 0,0,1, o_b + l*1280, nullptr, 1.f);
        ln_k<<<6000, 256, 0, stream>>>(x, h, ln2_g + l*1280, ln2_b + l*1280);
        dim3 g1(40, 47, 1);
        gemm_k<1><<<g1,256,0,stream>>>(h, fc1_w + (size_t)l*6553600, g, 6000,5120,1280, 1280,1280,5120,
            0,0,1, 0,0,1, 0,0,1, fc1_b + l*5120, nullptr, 1.f);
        gemm_k<2><<<gq,256,0,stream>>>(g, fc2_w + (size_t)l*6553600, x, 6000,1280,5120, 5120,5120,1280,
            0,0,1, 0,0,1, 0,0,1, fc2_b + l*1280, nullptr, 1.f);
    }

    // VQ: xn = x/||x||, dist = xn @ cb^T, code = argmax(2*dist - ||cb||^2)
    norm_k<<<6000, 256, 0, stream>>>(x, h);
    {
        dim3 gd(32, 47, 1);
        gemm_k<0><<<gd,256,0,stream>>>(h, codebook, dist, 6000,4096,1280, 1280,1280,4096,
            0,0,1, 0,0,1, 0,0,1, nullptr, nullptr, 1.f);
    }
    argmax_k<<<6000, 256, 0, stream>>>(dist, cbn2, outp);
    clen_k<<<1, 64, 0, stream>>>(mel_len, outp);
}

// Round 3
// 9228.719 us; speedup vs baseline: 1.8481x; 1.8481x over previous
//
#include <hip/hip_runtime.h>
#include <math.h>

// S3Tokenizer on MI355X — round 3.
// All matmuls: pre-split fp32 -> (hi,lo) bf16 pairs in global memory; GEMM is a
// pure bf16 4-tile kernel (Ah,Al,Bh,Bl) with 3 MFMAs per fragment pair
// (hh + hl + lh), global_load_lds width-16 staging (linear LDS dest,
// inverse-swizzled global source, swizzled ds_read), XCD-swizzled blockIdx.

#define DEVI __device__ __forceinline__
typedef __attribute__((ext_vector_type(8))) __bf16 bf16x8;
typedef __attribute__((ext_vector_type(4))) float f32x4;
typedef unsigned short u16;

DEVI float bitf(unsigned u){ return __builtin_bit_cast(float,u); }
DEVI unsigned fbit(float f){ return __builtin_bit_cast(unsigned,f); }
DEVI float gelu_f(float x){ return 0.5f*x*(1.0f+erff(x*0.7071067811865475f)); }
DEVI u16 bf_rne(float v){ unsigned u=fbit(v); return (u16)((u + 0x7FFFu + ((u>>16)&1u))>>16); }
DEVI void split2(float v, u16& h, u16& l){
    u16 hb = bf_rne(v);
    float hf = bitf(((unsigned)hb)<<16);
    l = bf_rne(v - hf);
    h = hb;
}

DEVI void gload16(const void* g, void* l){
    __builtin_amdgcn_global_load_lds((const __attribute__((address_space(1))) unsigned*)g,
                                     (__attribute__((address_space(3))) unsigned*)l, 16, 0, 0);
}

// stage one 128x32 bf16 tile (8KB) into lds region; LDS linear, global source
// pre-swizzled: LDS slot (r,c) holds global chunk (r, c^(r&3)).
DEVI void stage_arr(const char* gbase, int ldBytes, int tid, char* lds){
    #pragma unroll
    for (int j=0;j<2;j++){
        int s = tid + (j<<8);
        int r = s >> 2;
        int cg = (s & 3) ^ (r & 3);
        gload16(gbase + (long)r*ldBytes + (cg<<4), lds + (s<<4));
    }
}

// ---------------- GEMM: C[M,N] = epi(A[M,K] @ B[N,K]^T), pre-split bf16 ----
// EPI: 0 (acc+bias)*scale | 1 gelu(acc+bias) | 2 C += acc+bias | 3 gelu+pos_emb
// OUT: 0 fp32 Cf | 1 split pair (Ch, Cl)
template<int EPI, int OUT>
__global__ __launch_bounds__(256, 2) void gemm2_k(
    const u16* __restrict__ Ah, const u16* __restrict__ Al,
    const u16* __restrict__ Bh, const u16* __restrict__ Bl,
    float* __restrict__ Cf, u16* __restrict__ Ch, u16* __restrict__ Cl,
    int M, int N, int K, int lda, int ldb, int ldc,
    long sAo, long sAi, int dA,
    long sBo, long sBi, int dB,
    long sCo, long sCi, int dC,
    const float* __restrict__ bias, const float* __restrict__ aux, float scale)
{
    __shared__ char L[32768];   // Ah | Al | Bh | Bl, 8KB each

    const int tid = threadIdx.x;
    const int z = blockIdx.z;

    // bijective XCD swizzle over (x,y) plane (m204)
    int nwg = gridDim.x * gridDim.y;
    int wg  = blockIdx.y * gridDim.x + blockIdx.x;
    int q8 = nwg >> 3, r8 = nwg & 7;
    int xcd = wg & 7, off = wg >> 3;
    int wg2 = (xcd < r8 ? xcd*(q8+1) : r8*(q8+1) + (xcd-r8)*q8) + off;
    const int rowBase = (wg2 / gridDim.x) << 7;
    const int colBase = (wg2 % gridDim.x) << 7;

    const long zA = (long)(z / dA) * sAo + (long)(z % dA) * sAi;
    const long zB = (long)(z / dB) * sBo + (long)(z % dB) * sBi;
    const long cz = (long)(z / dC) * sCo + (long)(z % dC) * sCi;

    const u16* pAh = Ah + zA + (long)rowBase*lda;
    const u16* pAl = Al + zA + (long)rowBase*lda;
    const u16* pBh = Bh + zB + (long)colBase*ldb;
    const u16* pBl = Bl + zB + (long)colBase*ldb;
    const int lda2 = lda*2, ldb2 = ldb*2;

    const int lane = tid & 63;
    const int w    = tid >> 6;
    const int wr   = (w >> 1) << 6;
    const int wc   = (w & 1) << 6;
    const int fr   = lane & 15;
    const int kg   = lane >> 4;

    f32x4 acc[4][4];
    #pragma unroll
    for (int m=0;m<4;m++)
        #pragma unroll
        for (int n=0;n<4;n++) acc[m][n] = (f32x4){0.f,0.f,0.f,0.f};

    const int KT = K >> 5;
    for (int kt = 0; kt < KT; ++kt){
        const long kb = (long)kt << 5;
        __syncthreads();
        stage_arr((const char*)(pAh + kb), lda2, tid, L);
        stage_arr((const char*)(pAl + kb), lda2, tid, L + 8192);
        stage_arr((const char*)(pBh + kb), ldb2, tid, L + 16384);
        stage_arr((const char*)(pBl + kb), ldb2, tid, L + 24576);
        __syncthreads();

        bf16x8 ah[4], al[4], bh[4], bl[4];
        #pragma unroll
        for (int m=0;m<4;m++){
            int rr = wr + (m<<4) + fr;
            int ad = (rr<<6) + ((kg ^ (rr&3))<<4);
            ah[m] = *(const bf16x8*)(L + ad);
            al[m] = *(const bf16x8*)(L + 8192 + ad);
        }
        #pragma unroll
        for (int n=0;n<4;n++){
            int rr = wc + (n<<4) + fr;
            int ad = (rr<<6) + ((kg ^ (rr&3))<<4);
            bh[n] = *(const bf16x8*)(L + 16384 + ad);
            bl[n] = *(const bf16x8*)(L + 24576 + ad);
        }
        #pragma unroll
        for (int m=0;m<4;m++){
            #pragma unroll
            for (int n=0;n<4;n++){
                acc[m][n] = __builtin_amdgcn_mfma_f32_16x16x32_bf16(ah[m], bh[n], acc[m][n], 0,0,0);
                acc[m][n] = __builtin_amdgcn_mfma_f32_16x16x32_bf16(ah[m], bl[n], acc[m][n], 0,0,0);
                acc[m][n] = __builtin_amdgcn_mfma_f32_16x16x32_bf16(al[m], bh[n], acc[m][n], 0,0,0);
            }
        }
    }

    // C/D layout: col = lane&15, row = (lane>>4)*4 + j
    #pragma unroll
    for (int n=0;n<4;n++){
        int col = colBase + wc + (n<<4) + fr;
        if (col >= N) continue;
        float bv = bias ? bias[col] : 0.f;
        #pragma unroll
        for (int m=0;m<4;m++){
            int rbase = rowBase + wr + (m<<4) + (kg<<2);
            #pragma unroll
            for (int j=0;j<4;j++){
                int row = rbase + j;
                if (row >= M) continue;
                float v = acc[m][n][j];
                long ci = cz + (long)row*ldc + col;
                if (OUT == 0){
                    float* cp = Cf + ci;
                    if (EPI == 0)      *cp = (v + bv) * scale;
                    else if (EPI == 1) *cp = gelu_f(v + bv);
                    else if (EPI == 2) *cp = *cp + v + bv;
                    else               *cp = gelu_f(v + bv) + aux[(long)(row % 750)*1280 + col];
                } else {
                    float v2;
                    if (EPI == 0)      v2 = (v + bv) * scale;
                    else if (EPI == 1) v2 = gelu_f(v + bv);
                    else               v2 = v + bv;
                    u16 hs, ls; split2(v2, hs, ls);
                    Ch[ci] = hs; Cl[ci] = ls;
                }
            }
        }
    }
}

// ---------------- split conversion: fp32 -> (hi,lo) bf16 ----------------
__global__ __launch_bounds__(256) void split_k(const float* __restrict__ src,
                                               u16* __restrict__ dh, u16* __restrict__ dl, int n4)
{
    int stride = gridDim.x * 256;
    for (int i = blockIdx.x*256 + threadIdx.x; i < n4; i += stride){
        f32x4 v = *(const f32x4*)(src + (long)i*4);
        ushort4 hh, ll;
        split2(v.x, hh.x, ll.x); split2(v.y, hh.y, ll.y);
        split2(v.z, hh.z, ll.z); split2(v.w, hh.w, ll.w);
        *(ushort4*)(dh + (long)i*4) = hh;
        *(ushort4*)(dl + (long)i*4) = ll;
    }
}

// ---------------- small kernels ----------------

__global__ __launch_bounds__(256) void ln_k(const float* __restrict__ x,
                                            u16* __restrict__ hh, u16* __restrict__ hl,
                                            const float* __restrict__ g, const float* __restrict__ bb)
{
    __shared__ float red[8];
    int row = blockIdx.x, tid = threadIdx.x;
    const float* xr = x + (long)row * 1280;
    float v[5]; float s = 0.f;
    #pragma unroll
    for (int i=0;i<5;i++){ v[i] = xr[tid + (i<<8)]; s += v[i]; }
    #pragma unroll
    for (int m=32;m>=1;m>>=1) s += __shfl_xor(s, m, 64);
    if ((tid & 63) == 0) red[tid>>6] = s;
    __syncthreads();
    float mean = (red[0]+red[1]+red[2]+red[3]) * (1.f/1280.f);
    float qv = 0.f;
    #pragma unroll
    for (int i=0;i<5;i++){ float d = v[i]-mean; qv += d*d; }
    #pragma unroll
    for (int m=32;m>=1;m>>=1) qv += __shfl_xor(qv, m, 64);
    __syncthreads();
    if ((tid & 63) == 0) red[tid>>6] = qv;
    __syncthreads();
    float inv = 1.0f / sqrtf((red[0]+red[1]+red[2]+red[3]) * (1.f/1280.f) + 1e-5f);
    #pragma unroll
    for (int i=0;i<5;i++){
        int c = tid + (i<<8);
        float y = (v[i]-mean)*inv*g[c] + bb[c];
        u16 hs, ls; split2(y, hs, ls);
        hh[(long)row*1280 + c] = hs; hl[(long)row*1280 + c] = ls;
    }
}

__global__ __launch_bounds__(256) void norm_k(const float* __restrict__ x,
                                              u16* __restrict__ hh, u16* __restrict__ hl)
{
    __shared__ float red[8];
    int row = blockIdx.x, tid = threadIdx.x;
    const float* xr = x + (long)row * 1280;
    float v[5]; float s = 0.f;
    #pragma unroll
    for (int i=0;i<5;i++){ v[i] = xr[tid + (i<<8)]; s += v[i]*v[i]; }
    #pragma unroll
    for (int m=32;m>=1;m>>=1) s += __shfl_xor(s, m, 64);
    if ((tid & 63) == 0) red[tid>>6] = s;
    __syncthreads();
    float nrm = sqrtf(red[0]+red[1]+red[2]+red[3]);
    float sc = 1.0f / fmaxf(nrm, 1e-12f);
    #pragma unroll
    for (int i=0;i<5;i++){
        int c = tid + (i<<8);
        u16 hs, ls; split2(v[i]*sc, hs, ls);
        hh[(long)row*1280 + c] = hs; hl[(long)row*1280 + c] = ls;
    }
}

__global__ __launch_bounds__(256) void cbn2_k(const float* __restrict__ cb, float* __restrict__ cbn2)
{
    __shared__ float red[8];
    int row = blockIdx.x, tid = threadIdx.x;
    const float* cr = cb + (long)row * 1280;
    float s = 0.f;
    #pragma unroll
    for (int i=0;i<5;i++){ float t = cr[tid + (i<<8)]; s += t*t; }
    #pragma unroll
    for (int m=32;m>=1;m>>=1) s += __shfl_xor(s, m, 64);
    if ((tid & 63) == 0) red[tid>>6] = s;
    __syncthreads();
    if (tid == 0) cbn2[row] = red[0]+red[1]+red[2]+red[3];
}

// masked softmax, in-place: reads fp32 S row [768], writes P as (hi[768], lo[768])
// bf16 pair over the same 3072 bytes. Pad cols 750..767 zeroed.
__global__ __launch_bounds__(256) void softmax_k(float* __restrict__ S, const float* __restrict__ bv, int b0)
{
    __shared__ float red[8];
    int z = blockIdx.x / 750;
    int t = blockIdx.x % 750;
    int bg = b0 + z / 20;
    const float* bias = bv + bg * 750;
    float* Sr = S + (long)z*589824 + (long)t*768;
    int tid = threadIdx.x;
    float vals[3]; float mx = -3.0e38f;
    #pragma unroll
    for (int i=0;i<3;i++){
        int c = tid + (i<<8);
        if (c < 750){ vals[i] = Sr[c] + bias[c]; mx = fmaxf(mx, vals[i]); }
        else vals[i] = -3.0e38f;
    }
    #pragma unroll
    for (int m=32;m>=1;m>>=1) mx = fmaxf(mx, __shfl_xor(mx, m, 64));
    if ((tid & 63) == 0) red[tid>>6] = mx;
    __syncthreads();
    mx = fmaxf(fmaxf(red[0],red[1]), fmaxf(red[2],red[3]));
    float s = 0.f;
    #pragma unroll
    for (int i=0;i<3;i++){
        int c = tid + (i<<8);
        if (c < 750){ vals[i] = expf(vals[i] - mx); s += vals[i]; }
    }
    #pragma unroll
    for (int m=32;m>=1;m>>=1) s += __shfl_xor(s, m, 64);
    __syncthreads();
    if ((tid & 63) == 0) red[tid>>6] = s;
    __syncthreads();
    float inv = 1.0f / (red[0]+red[1]+red[2]+red[3]);
    u16* ph = (u16*)Sr;
    u16* pl = ph + 768;
    #pragma unroll
    for (int i=0;i<3;i++){
        int c = tid + (i<<8);
        float pv = (c < 750) ? vals[i]*inv : 0.f;
        u16 hs, ls; split2(pv, hs, ls);
        ph[c] = hs; pl[c] = ls;
    }
}

// V^T per (b,head): copy hi/lo directly (no arithmetic). vt[bh*64+d][t], ld 768,
// zero-filled t in [750,768).
__global__ __launch_bounds__(256) void vtrans_k(const u16* __restrict__ qh, const u16* __restrict__ ql,
                                                u16* __restrict__ vh, u16* __restrict__ vl)
{
    __shared__ u16 th[64][72], tl[64][72];
    int bh = blockIdx.y; int b = bh / 20, hh = bh % 20;
    int t0 = blockIdx.x * 64;
    int tid = threadIdx.x;
    int tj = tid & 63;
    int ti4 = tid >> 6;
    #pragma unroll
    for (int i=0;i<16;i++){
        int tt = ti4 + i*4;
        int t = t0 + tt;
        long src = ((long)(b*750 + t))*3840 + 2560 + hh*64 + tj;
        bool ok = t < 750;
        th[tt][tj] = ok ? qh[src] : (u16)0;
        tl[tt][tj] = ok ? ql[src] : (u16)0;
    }
    __syncthreads();
    #pragma unroll
    for (int i=0;i<16;i++){
        int d = ti4 + i*4;
        long dst = ((long)(bh*64 + d))*768 + (t0 + tj);
        vh[dst] = th[tj][d];
        vl[dst] = tl[tj][d];
    }
}

// im2col conv1 -> split pair: A1[(b*1500+t)][i*3+k]
__global__ __launch_bounds__(128) void im2col1_k(const float* __restrict__ mel,
                                                 u16* __restrict__ ah, u16* __restrict__ al)
{
    int row = blockIdx.x;
    int b = row / 1500, t = row % 1500;
    int i = threadIdx.x;
    const float* mp = mel + ((long)(b*128 + i))*3000;
    long o = (long)row*384 + i*3;
    #pragma unroll
    for (int k=0;k<3;k++){
        int u = 2*t - 1 + k;
        float v = (u >= 0 && u < 3000) ? mp[u] : 0.f;
        u16 hs, ls; split2(v, hs, ls);
        ah[o+k] = hs; al[o+k] = ls;
    }
}

// im2col conv2 -> split pair: A2[(b*750+t)][i*3+k] from y1 fp32
__global__ __launch_bounds__(256) void im2col2_k(const float* __restrict__ y1,
                                                 u16* __restrict__ ah, u16* __restrict__ al)
{
    int row = blockIdx.x;
    int b = row / 750, t = row % 750;
    int tid = threadIdx.x;
    for (int s5=0;s5<5;s5++){
        int i = tid + (s5<<8);
        long o = (long)row*3840 + i*3;
        #pragma unroll
        for (int k=0;k<3;k++){
            int u = 2*t - 1 + k;
            float v = (u >= 0 && u < 1500) ? y1[((long)(b*1500 + u))*1280 + i] : 0.f;
            u16 hs, ls; split2(v, hs, ls);
            ah[o+k] = hs; al[o+k] = ls;
        }
    }
}

__global__ void biasv_k(const int* __restrict__ mel_len, float* __restrict__ bv)
{
    int idx = blockIdx.x*256 + threadIdx.x;
    if (idx < 6000){
        int b = idx / 750, t = idx % 750;
        bv[idx] = (4*t + 3 < mel_len[b]) ? 0.f : -1e10f;
    }
}

__global__ __launch_bounds__(256) void argmax_k(const float* __restrict__ dist, const float* __restrict__ cbn2,
                                                int* __restrict__ outp)
{
    __shared__ float bvs[256];
    __shared__ int   bis[256];
    int row = blockIdx.x, tid = threadIdx.x;
    const float* dr = dist + (long)row * 4096;
    float best = -3.0e38f; int bidx = 0x7fffffff;
    for (int i=0;i<16;i++){
        int n = tid + (i<<8);
        float v = 2.f*dr[n] - cbn2[n];
        if (v > best || (v == best && n < bidx)){ best = v; bidx = n; }
    }
    bvs[tid] = best; bis[tid] = bidx;
    __syncthreads();
    for (int s=128;s>0;s>>=1){
        if (tid < s){
            if (bvs[tid+s] > bvs[tid] || (bvs[tid+s] == bvs[tid] && bis[tid+s] < bis[tid])){
                bvs[tid] = bvs[tid+s]; bis[tid] = bis[tid+s];
            }
        }
        __syncthreads();
    }
    if (tid == 0) outp[row] = bis[0];
}

__global__ void clen_k(const int* __restrict__ mel_len, int* __restrict__ outp)
{
    int b = threadIdx.x;
    if (b < 8){
        int l1 = (mel_len[b] + 1) >> 1;
        outp[6000 + b] = (l1 + 1) >> 1;
    }
}

// ---------------- host ----------------

static inline void do_split(const float* src, u16* dh, u16* dl, long n, hipStream_t st){
    int n4 = (int)(n >> 2);
    int grid = (n4 + 255) / 256; if (grid > 2048) grid = 2048;
    split_k<<<grid, 256, 0, st>>>(src, dh, dl, n4);
}

extern "C" void kernel_launch(void* const* d_in, const int* in_sizes, int n_in,
                              void* d_out, int out_size, void* d_ws, size_t ws_size,
                              hipStream_t stream)
{
    const float* mel      = (const float*)d_in[0];
    const int*   mel_len  = (const int*)  d_in[1];
    const float* conv1_w  = (const float*)d_in[2];
    const float* conv1_b  = (const float*)d_in[3];
    const float* conv2_w  = (const float*)d_in[4];
    const float* conv2_b  = (const float*)d_in[5];
    const float* pos_emb  = (const float*)d_in[6];
    const float* ln1_g    = (const float*)d_in[7];
    const float* ln1_b    = (const float*)d_in[8];
    const float* q_w      = (const float*)d_in[9];
    const float* q_b      = (const float*)d_in[10];
    const float* k_w      = (const float*)d_in[11];
    const float* v_w      = (const float*)d_in[12];
    const float* v_b      = (const float*)d_in[13];
    const float* o_w      = (const float*)d_in[14];
    const float* o_b      = (const float*)d_in[15];
    const float* ln2_g    = (const float*)d_in[16];
    const float* ln2_b    = (const float*)d_in[17];
    const float* fc1_w    = (const float*)d_in[18];
    const float* fc1_b    = (const float*)d_in[19];
    const float* fc2_w    = (const float*)d_in[20];
    const float* fc2_b    = (const float*)d_in[21];
    const float* codebook = (const float*)d_in[22];
    int* outp = (int*)d_out;
    char* base = (char*)d_ws;

    // byte allocator, 256B aligned
    size_t off = 0;
    auto alloc = [&](size_t bytes)->size_t{ size_t o = off; off = (off + bytes + 255) & ~(size_t)255; return o; };

    size_t o_x  = alloc(30801920);          // x fp32 [6016][1280]
    size_t o_hh = alloc(15400960), o_hl = alloc(15400960);   // h pair [6016][1280]
    size_t o_qh = alloc(47185920), o_ql = alloc(47185920);   // qkv pair [6144][3840]
    size_t o_vh = alloc(15925248), o_vl = alloc(15925248);   // vt pair [10368][768]
    size_t o_ah = alloc(15400960), o_al = alloc(15400960);   // ab pair [6016][1280]
    size_t o_gh = alloc(61603840), o_gl = alloc(61603840);   // g pair [6016][5120]
    size_t o_wqh= alloc(3276800),  o_wql= alloc(3276800);
    size_t o_wkh= alloc(3276800),  o_wkl= alloc(3276800);
    size_t o_wvh= alloc(3276800),  o_wvl= alloc(3276800);
    size_t o_woh= alloc(3276800),  o_wol= alloc(3276800);
    size_t o_w1h= alloc(13107200), o_w1l= alloc(13107200);
    size_t o_w2h= alloc(13107200), o_w2l= alloc(13107200);
    size_t o_bv = alloc(24576);
    size_t o_c2 = alloc(16384);
    size_t base_end = off;

    float* x    = (float*)(base + o_x);
    u16 *hh = (u16*)(base+o_hh), *hl = (u16*)(base+o_hl);
    u16 *qh = (u16*)(base+o_qh), *ql = (u16*)(base+o_ql);
    u16 *vh = (u16*)(base+o_vh), *vl = (u16*)(base+o_vl);
    u16 *abh= (u16*)(base+o_ah), *abl= (u16*)(base+o_al);
    u16 *gh = (u16*)(base+o_gh), *gl = (u16*)(base+o_gl);
    float* bv   = (float*)(base + o_bv);
    float* cbn2 = (float*)(base + o_c2);
    float* y1   = (float*)(base + o_gh);    // conv phase alias (61.6MB exact)
    u16 *a1h = abh, *a1l = abl;             // conv phase alias (9.2MB <= 15.4)
    u16 *a2h = qh,  *a2l = ql;              // conv phase alias (46.2MB <= 47.2)
    float* dist = (float*)(base + o_gh);    // VQ phase alias (98.3MB <= 123.2)

    // attention S/P region: dedicated if it fits, else alias g region (nb=2)
    const size_t S_unit = 47185920;   // bytes per batch (20 heads x 768 x 768 x 4B)
    int nb; float* Sb;
    if      (ws_size >= base_end + 8*S_unit){ nb = 8; Sb = (float*)(base + alloc(8*S_unit)); }
    else if (ws_size >= base_end + 4*S_unit){ nb = 4; Sb = (float*)(base + alloc(4*S_unit)); }
    else if (ws_size >= base_end + 2*S_unit){ nb = 2; Sb = (float*)(base + alloc(2*S_unit)); }
    else    { nb = 2; Sb = (float*)(base + o_gh); }
    int nch = 8 / nb;

    biasv_k<<<24, 256, 0, stream>>>(mel_len, bv);
    cbn2_k<<<4096, 256, 0, stream>>>(codebook, cbn2);

    // ---- conv1: y1 = gelu(A1 @ W1^T + b1), [12000][1280]
    u16 *c1h = (u16*)(base+o_wqh), *c1l = (u16*)(base+o_wql);
    do_split(conv1_w, c1h, c1l, 491520, stream);
    im2col1_k<<<12000, 128, 0, stream>>>(mel, a1h, a1l);
    {
        dim3 grid(10, 94, 1);
        gemm2_k<1,0><<<grid, 256, 0, stream>>>(a1h, a1l, c1h, c1l, y1, nullptr, nullptr,
            12000,1280,384, 384,384,1280, 0,0,1, 0,0,1, 0,0,1, conv1_b, nullptr, 1.f);
    }
    // ---- conv2 (+ transpose + pos_emb): x [6000][1280]
    u16 *c2h = (u16*)(base+o_w1h), *c2l = (u16*)(base+o_w1l);
    do_split(conv2_w, c2h, c2l, 4915200, stream);
    im2col2_k<<<6000, 256, 0, stream>>>(y1, a2h, a2l);
    {
        dim3 grid(10, 47, 1);
        gemm2_k<3,0><<<grid, 256, 0, stream>>>(a2h, a2l, c2h, c2l, x, nullptr, nullptr,
            6000,1280,3840, 3840,3840,1280, 0,0,1, 0,0,1, 0,0,1, conv2_b, pos_emb, 1.f);
    }

    u16 *wqh=(u16*)(base+o_wqh), *wql=(u16*)(base+o_wql);
    u16 *wkh=(u16*)(base+o_wkh), *wkl=(u16*)(base+o_wkl);
    u16 *wvh=(u16*)(base+o_wvh), *wvl=(u16*)(base+o_wvl);
    u16 *woh=(u16*)(base+o_woh), *wol=(u16*)(base+o_wol);
    u16 *w1h=(u16*)(base+o_w1h), *w1l=(u16*)(base+o_w1l);
    u16 *w2h=(u16*)(base+o_w2h), *w2l=(u16*)(base+o_w2l);

    const float qsc = 0.35355339059327373f; // 64^-0.25
    dim3 gq(10, 47, 1);
    for (int l = 0; l < 6; ++l){
        do_split(q_w  + (size_t)l*1638400, wqh, wql, 1638400, stream);
        do_split(k_w  + (size_t)l*1638400, wkh, wkl, 1638400, stream);
        do_split(v_w  + (size_t)l*1638400, wvh, wvl, 1638400, stream);
        do_split(o_w  + (size_t)l*1638400, woh, wol, 1638400, stream);
        do_split(fc1_w+ (size_t)l*6553600, w1h, w1l, 6553600, stream);
        do_split(fc2_w+ (size_t)l*6553600, w2h, w2l, 6553600, stream);

        ln_k<<<6000, 256, 0, stream>>>(x, hh, hl, ln1_g + l*1280, ln1_b + l*1280);
        gemm2_k<0,1><<<gq,256,0,stream>>>(hh,hl, wqh,wql, nullptr, qh,      ql,
            6000,1280,1280, 1280,1280,3840, 0,0,1, 0,0,1, 0,0,1, q_b + l*1280, nullptr, qsc);
        gemm2_k<0,1><<<gq,256,0,stream>>>(hh,hl, wkh,wkl, nullptr, qh+1280, ql+1280,
            6000,1280,1280, 1280,1280,3840, 0,0,1, 0,0,1, 0,0,1, nullptr, nullptr, qsc);
        gemm2_k<0,1><<<gq,256,0,stream>>>(hh,hl, wvh,wvl, nullptr, qh+2560, ql+2560,
            6000,1280,1280, 1280,1280,3840, 0,0,1, 0,0,1, 0,0,1, v_b + l*1280, nullptr, 1.f);
        vtrans_k<<<dim3(12,160), 256, 0, stream>>>(qh, ql, vh, vl);

        for (int c = 0; c < nch; ++c){
            int b0 = c * nb;
            long aoff = (long)b0*2880000;
            dim3 gs(6, 6, nb*20);
            gemm2_k<0,0><<<gs,256,0,stream>>>(qh+aoff, ql+aoff, qh+aoff+1280, ql+aoff+1280,
                Sb, nullptr, nullptr,
                750,750,64, 3840,3840,768,
                2880000,64,20, 2880000,64,20, 589824,0,1, nullptr, nullptr, 1.f);
            softmax_k<<<nb*20*750, 256, 0, stream>>>(Sb, bv, b0);
            dim3 gp(1, 6, nb*20);
            gemm2_k<0,1><<<gp,256,0,stream>>>((u16*)Sb, (u16*)Sb+768,
                vh + (long)b0*983040, vl + (long)b0*983040,
                nullptr, abh + (long)b0*960000, abl + (long)b0*960000,
                750,64,768, 1536,768,1280,
                1179648,0,1, 49152,0,1, 960000,64,20, nullptr, nullptr, 1.f);
        }

        gemm2_k<2,0><<<gq,256,0,stream>>>(abh,abl, woh,wol, x, nullptr, nullptr,
            6000,1280,1280, 1280,1280,1280, 0,0,1, 0,0,1, 0,0,1, o_b + l*1280, nullptr, 1.f);
        ln_k<<<6000, 256, 0, stream>>>(x, hh, hl, ln2_g + l*1280, ln2_b + l*1280);
        dim3 g1(40, 47, 1);
        gemm2_k<1,1><<<g1,256,0,stream>>>(hh,hl, w1h,w1l, nullptr, gh, gl,
            6000,5120,1280, 1280,1280,5120, 0,0,1, 0,0,1, 0,0,1, fc1_b + l*5120, nullptr, 1.f);
        gemm2_k<2,0><<<gq,256,0,stream>>>(gh,gl, w2h,w2l, x, nullptr, nullptr,
            6000,1280,5120, 5120,5120,1280, 0,0,1, 0,0,1, 0,0,1, fc2_b + l*1280, nullptr, 1.f);
    }

    // ---- VQ
    norm_k<<<6000, 256, 0, stream>>>(x, hh, hl);
    do_split(codebook, w1h, w1l, 5242880, stream);
    {
        dim3 gd(32, 47, 1);
        gemm2_k<0,0><<<gd,256,0,stream>>>(hh,hl, w1h,w1l, dist, nullptr, nullptr,
            6000,4096,1280, 1280,1280,4096, 0,0,1, 0,0,1, 0,0,1, nullptr, nullptr, 1.f);
    }
    argmax_k<<<6000, 256, 0, stream>>>(dist, cbn2, outp);
    clen_k<<<1, 64, 0, stream>>>(mel_len, outp);
}